// Round 6
// baseline (595.620 us; speedup 1.0000x reference)
//
#include <hip/hip_runtime.h>
#include <hip/hip_bf16.h>

#define USER_NUM 50000
#define ITEM_NUM 20000
#define NNODE    70000
#define DD       64
#define SCAN_T   1024
#define NB_U2    1000
#define NB_I2    400
#define NSTRIPE  256   // scatter: stripes per group; grid = 8*NSTRIPE blocks

__device__ __forceinline__ const float* feat_row(const float* __restrict__ ue,
                                                 const float* __restrict__ ie, int n) {
    return (n < USER_NUM) ? (ue + (size_t)n * DD)
                          : (ie + (size_t)(n - USER_NUM) * DD);
}

// ---- CSR build: histogram -> block scan -> grouped scatter -----------------

__global__ __launch_bounds__(256) void hist_kernel(const int* __restrict__ erow,
                                                   int* __restrict__ cnt, int E) {
    const int stride = gridDim.x * blockDim.x;
    for (int e = blockIdx.x * blockDim.x + threadIdx.x; e < E; e += stride)
        atomicAdd(&cnt[erow[e]], 1);
}

__global__ __launch_bounds__(SCAN_T) void scan_kernel(const int* __restrict__ cnt,
                                                      int* __restrict__ base) {
    __shared__ int s[SCAN_T];
    const int t = threadIdx.x;
    const int CH = (NNODE + SCAN_T - 1) / SCAN_T;   // 69
    const int lo = t * CH;
    const int hi = min(lo + CH, NNODE);
    int sum = 0;
    for (int i = lo; i < hi; ++i) sum += cnt[i];
    s[t] = sum;
    __syncthreads();
    for (int off = 1; off < SCAN_T; off <<= 1) {
        int v = s[t];
        int u = (t >= off) ? s[t - off] : 0;
        __syncthreads();
        s[t] = v + u;
        __syncthreads();
    }
    int running = s[t] - sum;
    for (int i = lo; i < hi; ++i) {
        base[i] = running;
        running += cnt[i];
    }
    if (t == SCAN_T - 1) base[NNODE] = s[SCAN_T - 1];
}

// Destination-grouped scatter. Group g owns rows [g*NNODE/8, ...), i.e. a
// contiguous ~2MB slice of epair. Blocks with (blockIdx&7)==g handle only
// group-g edges, so (assuming round-robin block->XCD) each epair cache line
// is written by a single XCD's L2 and partial stores merge into full-line
// writebacks. Grouping is a PERF heuristic only; correctness needs nothing
// about XCD placement. cursor pre-initialized to base -> absolute slots.
__global__ __launch_bounds__(256) void scatter_kernel(
    const int* __restrict__ erow, const int* __restrict__ ecol,
    const float* __restrict__ eval,
    int* __restrict__ cursor, int2* __restrict__ epair, int E) {
    const int g    = blockIdx.x & 7;
    const int rank = blockIdx.x >> 3;                 // 0..NSTRIPE-1
    const int CH   = (E + NSTRIPE - 1) / NSTRIPE;
    const int lo   = rank * CH;
    const int hi   = min(lo + CH, E);
    for (int e = lo + (int)threadIdx.x; e < hi; e += 256) {
        const int r = erow[e];
        const int gr = (r * 8) / NNODE;               // const div -> magic mul
        if (gr == g) {
            const int pos = atomicAdd(&cursor[r], 1);
            epair[pos] = make_int2(ecol[e], __float_as_int(eval[e]));
        }
    }
}

// ---- SpMM, gather form, scalarized edge stream, 8 gathers in flight --------
// Stores a1 = lx + f (self term folded) and a2 = lx2.

__global__ __launch_bounds__(256) void spmm_kernel(
    const float* __restrict__ ue, const float* __restrict__ ie,
    const int2* __restrict__ epair, const int* __restrict__ base,
    float* __restrict__ lx, float* __restrict__ lx2) {
    const int lane = threadIdx.x & 63;
    int wv = (int)((blockIdx.x * blockDim.x + threadIdx.x) >> 6);
    wv = __builtin_amdgcn_readfirstlane(wv);
    const int nw = (int)((gridDim.x * blockDim.x) >> 6);
    for (int r = wv; r < NNODE; r += nw) {
        const int jb = base[r];
        const int je = base[r + 1];
        float acc1 = 0.f, acc2 = 0.f;
        int j = jb;
        for (; j + 8 <= je; j += 8) {
            int2 p[8];
#pragma unroll
            for (int t = 0; t < 8; ++t) p[t] = epair[j + t];
            float f[8];
#pragma unroll
            for (int t = 0; t < 8; ++t) f[t] = feat_row(ue, ie, p[t].x)[lane];
#pragma unroll
            for (int t = 0; t < 8; ++t) {
                const float v = __int_as_float(p[t].y);
                acc1 = fmaf(v, f[t], acc1);
                acc2 = fmaf(v * f[t], f[t], acc2);
            }
        }
        for (; j + 4 <= je; j += 4) {
            int2 p[4];
#pragma unroll
            for (int t = 0; t < 4; ++t) p[t] = epair[j + t];
            float f[4];
#pragma unroll
            for (int t = 0; t < 4; ++t) f[t] = feat_row(ue, ie, p[t].x)[lane];
#pragma unroll
            for (int t = 0; t < 4; ++t) {
                const float v = __int_as_float(p[t].y);
                acc1 = fmaf(v, f[t], acc1);
                acc2 = fmaf(v * f[t], f[t], acc2);
            }
        }
        for (; j < je; ++j) {
            const int2 p = epair[j];
            const float f = feat_row(ue, ie, p.x)[lane];
            const float v = __int_as_float(p.y);
            acc1 = fmaf(v, f, acc1);
            acc2 = fmaf(v * f, f, acc2);
        }
        lx [(size_t)r * DD + lane] = acc1 + feat_row(ue, ie, r)[lane];
        lx2[(size_t)r * DD + lane] = acc2;
    }
}

// ---- GCN transform, zero-LDS, alias-free -----------------------------------
// h = leaky_relu(a1@Wg1 + a2@Wg2 + bg1 + bg2); h is a DISTINCT buffer now,
// so scalar activation loads pipeline across rows.

__global__ __launch_bounds__(256) void gcn_h_kernel(
    const float* __restrict__ a1, const float* __restrict__ a2,
    const float* __restrict__ Wg1, const float* __restrict__ bg1,
    const float* __restrict__ Wg2, const float* __restrict__ bg2,
    float* __restrict__ h) {
    const int lane = threadIdx.x & 63;
    float w1[DD], w2[DD];
#pragma unroll
    for (int k = 0; k < DD; ++k) {
        w1[k] = Wg1[k * DD + lane];
        w2[k] = Wg2[k * DD + lane];
    }
    const float bias = bg1[lane] + bg2[lane];
    int wv = (int)((blockIdx.x * blockDim.x + threadIdx.x) >> 6);
    wv = __builtin_amdgcn_readfirstlane(wv);
    const int nw = (int)((gridDim.x * blockDim.x) >> 6);
    for (int r = wv; r < NNODE; r += nw) {
        const float* ar = a1 + (size_t)r * DD;
        const float* br = a2 + (size_t)r * DD;
        float o0 = bias, o1 = 0.f, o2 = 0.f, o3 = 0.f;
#pragma unroll
        for (int k = 0; k < DD; k += 2) {
            o0 = fmaf(ar[k],     w1[k],     o0);
            o1 = fmaf(ar[k + 1], w1[k + 1], o1);
            o2 = fmaf(br[k],     w2[k],     o2);
            o3 = fmaf(br[k + 1], w2[k + 1], o3);
        }
        const float x = (o0 + o1) + (o2 + o3);
        h[(size_t)r * DD + lane] = (x > 0.f) ? x : 0.01f * x;
    }
}

// ---- Per-node MLP layer-1 partial, zero-LDS --------------------------------
// user: part[n] = f@W1[0:64]   + h@W1[64:128]  + b1
// item: part[n] = f@W1[128:192]+ h@W1[192:256]

__global__ __launch_bounds__(256) void part_kernel(
    const float* __restrict__ ue, const float* __restrict__ ie,
    const float* __restrict__ h,
    const float* __restrict__ W1, const float* __restrict__ b1,
    float* __restrict__ part) {
    const bool is_user = blockIdx.x < NB_U2;
    const float* Wh = W1 + (is_user ? 0 : 2 * DD * DD);
    const int lane = threadIdx.x & 63;
    float wa[DD], wb[DD];
#pragma unroll
    for (int k = 0; k < DD; ++k) {
        wa[k] = Wh[k * DD + lane];
        wb[k] = Wh[(DD + k) * DD + lane];
    }
    const float bias = is_user ? b1[lane] : 0.f;
    const float* fb  = is_user ? ue : ie;
    const int count  = is_user ? USER_NUM : ITEM_NUM;
    const int nbase  = is_user ? 0 : USER_NUM;
    const int nwav   = (is_user ? NB_U2 : NB_I2) * 4;
    int lw = (is_user ? blockIdx.x : blockIdx.x - NB_U2) * 4 + (int)(threadIdx.x >> 6);
    lw = __builtin_amdgcn_readfirstlane(lw);
    for (int idx = lw; idx < count; idx += nwav) {
        const float* fr = fb + (size_t)idx * DD;
        const float* hr = h + (size_t)(nbase + idx) * DD;
        float p0 = bias, p1 = 0.f, p2 = 0.f, p3 = 0.f;
#pragma unroll
        for (int k = 0; k < DD; k += 2) {
            p0 = fmaf(fr[k],     wa[k],     p0);
            p1 = fmaf(fr[k + 1], wa[k + 1], p1);
            p2 = fmaf(hr[k],     wb[k],     p2);
            p3 = fmaf(hr[k + 1], wb[k + 1], p3);
        }
        part[(size_t)(nbase + idx) * DD + lane] = (p0 + p1) + (p2 + p3);
    }
}

// ---- Per-sample MLP: o1 = relu(part_u + part_i); layers 2,3 ----------------

__global__ __launch_bounds__(256) void mlp_kernel(
    const float* __restrict__ part,
    const float* __restrict__ W2, const float* __restrict__ b2,
    const float* __restrict__ W3, const float* __restrict__ b3,
    const int* __restrict__ uid, const int* __restrict__ iid,
    float* __restrict__ out, int B) {
    __shared__ float sW2[DD * 32];
    __shared__ float sW3[32];
    for (int i = threadIdx.x; i < DD * 32; i += 256) sW2[i] = W2[i];
    if (threadIdx.x < 32) sW3[threadIdx.x] = W3[threadIdx.x];
    __syncthreads();
    const int lane = threadIdx.x & 63;
    const int wave = (int)((blockIdx.x * blockDim.x + threadIdx.x) >> 6);
    const int nw   = (int)((gridDim.x * blockDim.x) >> 6);
    const float bias2 = b2[lane & 31];
    const float w3v   = sW3[lane & 31];
    const float bias3 = b3[0];
    for (int s = wave; s < B; s += nw) {
        const int u  = uid[s];
        const int it = iid[s];
        const float pu = part[(size_t)u * DD + lane];
        const float pi = part[(size_t)(USER_NUM + it) * DD + lane];
        const float x  = pu + pi;
        const float o1 = (x > 0.f) ? x : 0.f;
        float acc_a = bias2, acc_b = 0.f;
#pragma unroll
        for (int k = 0; k < DD; k += 2) {
            acc_a = fmaf(__shfl(o1, k),     sW2[k * 32 + (lane & 31)],       acc_a);
            acc_b = fmaf(__shfl(o1, k + 1), sW2[(k + 1) * 32 + (lane & 31)], acc_b);
        }
        const float a2 = acc_a + acc_b;
        const float o2 = (a2 > 0.f) ? a2 : 0.f;
        float p = o2 * w3v;
        p += __shfl_xor(p, 1);
        p += __shfl_xor(p, 2);
        p += __shfl_xor(p, 4);
        p += __shfl_xor(p, 8);
        p += __shfl_xor(p, 16);
        if (lane == 0) out[s] = p + bias3;
    }
}

extern "C" void kernel_launch(void* const* d_in, const int* in_sizes, int n_in,
                              void* d_out, int out_size, void* d_ws, size_t ws_size,
                              hipStream_t stream) {
    const float* ue   = (const float*)d_in[0];
    const float* ie   = (const float*)d_in[1];
    const int*   erow = (const int*)d_in[2];
    const int*   ecol = (const int*)d_in[3];
    const float* evalp= (const float*)d_in[4];
    const float* Wg1  = (const float*)d_in[5];
    const float* bg1  = (const float*)d_in[6];
    const float* Wg2  = (const float*)d_in[7];
    const float* bg2  = (const float*)d_in[8];
    const float* W1   = (const float*)d_in[9];
    const float* b1   = (const float*)d_in[10];
    const float* W2   = (const float*)d_in[11];
    const float* b2   = (const float*)d_in[12];
    const float* W3   = (const float*)d_in[13];
    const float* b3   = (const float*)d_in[14];
    const int*   uid  = (const int*)d_in[15];
    const int*   iid  = (const int*)d_in[16];
    float* out = (float*)d_out;

    const int E = in_sizes[2];
    const int B = in_sizes[15];

    // workspace (53.76 MB total, same as the round-1 footprint):
    //   [lx 17.92MB][lx2 17.92MB][epair 16MB][cnt .28][cursor .28][base .28]
    // h (17.92MB) OVERLAYS [epair..base+1MB] — all dead once spmm finishes.
    // part reuses lx2 (dead after gcn_h).
    char* ws = (char*)d_ws;
    const size_t nd = (size_t)NNODE * DD;
    float* lx    = (float*)ws;
    float* lx2   = lx + nd;
    float* part  = lx2;                                     // alias (lx2 dead)
    char*  tail  = ws + 2 * nd * sizeof(float);
    int2*  epair = (int2*)tail;
    int*   cnt   = (int*)(tail + (size_t)E * sizeof(int2));
    int*   cursor= cnt + NNODE;
    int*   base  = cursor + NNODE;                          // NNODE+1 ints
    float* h     = (float*)tail;                            // overlays epair..base

    hipMemsetAsync(cnt, 0, NNODE * sizeof(int), stream);

    hist_kernel<<<2048, 256, 0, stream>>>(erow, cnt, E);
    scan_kernel<<<1, SCAN_T, 0, stream>>>(cnt, base);
    hipMemcpyAsync(cursor, base, NNODE * sizeof(int), hipMemcpyDeviceToDevice, stream);
    scatter_kernel<<<8 * NSTRIPE, 256, 0, stream>>>(erow, ecol, evalp, cursor, epair, E);
    spmm_kernel<<<4096, 256, 0, stream>>>(ue, ie, epair, base, lx, lx2);
    gcn_h_kernel<<<1024, 256, 0, stream>>>(lx, lx2, Wg1, bg1, Wg2, bg2, h);
    part_kernel<<<NB_U2 + NB_I2, 256, 0, stream>>>(ue, ie, h, W1, b1, part);
    mlp_kernel<<<1024, 256, 0, stream>>>(part, W2, b2, W3, b3, uid, iid, out, B);
}

// Round 7
// 589.828 us; speedup vs baseline: 1.0098x; 1.0098x over previous
//
#include <hip/hip_runtime.h>
#include <hip/hip_bf16.h>

#define USER_NUM 50000
#define ITEM_NUM 20000
#define NNODE    70000
#define DD       64
#define SCAN_T   1024
#define NB_U2    1000
#define NB_I2    400
#define NSTRIPE  256   // scatter: stripes per group; grid = 8*NSTRIPE blocks

__device__ __forceinline__ const float* feat_row(const float* __restrict__ ue,
                                                 const float* __restrict__ ie, int n) {
    return (n < USER_NUM) ? (ue + (size_t)n * DD)
                          : (ie + (size_t)(n - USER_NUM) * DD);
}

// ---- CSR build: histogram -> block scan -> grouped scatter -----------------

__global__ __launch_bounds__(256) void hist_kernel(const int* __restrict__ erow,
                                                   int* __restrict__ cnt, int E) {
    const int stride = gridDim.x * blockDim.x;
    for (int e = blockIdx.x * blockDim.x + threadIdx.x; e < E; e += stride)
        atomicAdd(&cnt[erow[e]], 1);
}

__global__ __launch_bounds__(SCAN_T) void scan_kernel(const int* __restrict__ cnt,
                                                      int* __restrict__ base) {
    __shared__ int s[SCAN_T];
    const int t = threadIdx.x;
    const int CH = (NNODE + SCAN_T - 1) / SCAN_T;   // 69
    const int lo = t * CH;
    const int hi = min(lo + CH, NNODE);
    int sum = 0;
    for (int i = lo; i < hi; ++i) sum += cnt[i];
    s[t] = sum;
    __syncthreads();
    for (int off = 1; off < SCAN_T; off <<= 1) {
        int v = s[t];
        int u = (t >= off) ? s[t - off] : 0;
        __syncthreads();
        s[t] = v + u;
        __syncthreads();
    }
    int running = s[t] - sum;
    for (int i = lo; i < hi; ++i) {
        base[i] = running;
        running += cnt[i];
    }
    if (t == SCAN_T - 1) base[NNODE] = s[SCAN_T - 1];
}

// Destination-grouped scatter (see round-5 notes). Perf heuristic only.
__global__ __launch_bounds__(256) void scatter_kernel(
    const int* __restrict__ erow, const int* __restrict__ ecol,
    const float* __restrict__ eval,
    int* __restrict__ cursor, int2* __restrict__ epair, int E) {
    const int g    = blockIdx.x & 7;
    const int rank = blockIdx.x >> 3;                 // 0..NSTRIPE-1
    const int CH   = (E + NSTRIPE - 1) / NSTRIPE;
    const int lo   = rank * CH;
    const int hi   = min(lo + CH, E);
    for (int e = lo + (int)threadIdx.x; e < hi; e += 256) {
        const int r = erow[e];
        const int gr = (r * 8) / NNODE;               // const div -> magic mul
        if (gr == g) {
            const int pos = atomicAdd(&cursor[r], 1);
            epair[pos] = make_int2(ecol[e], __float_as_int(eval[e]));
        }
    }
}

// ---- SpMM, gather form, scalarized edge stream, 8 gathers in flight --------
// Stores a1 = lx + f (self term folded) and a2 = lx2.

__global__ __launch_bounds__(256) void spmm_kernel(
    const float* __restrict__ ue, const float* __restrict__ ie,
    const int2* __restrict__ epair, const int* __restrict__ base,
    float* __restrict__ lx, float* __restrict__ lx2) {
    const int lane = threadIdx.x & 63;
    int wv = (int)((blockIdx.x * blockDim.x + threadIdx.x) >> 6);
    wv = __builtin_amdgcn_readfirstlane(wv);
    const int nw = (int)((gridDim.x * blockDim.x) >> 6);
    for (int r = wv; r < NNODE; r += nw) {
        const int jb = base[r];
        const int je = base[r + 1];
        float acc1 = 0.f, acc2 = 0.f;
        int j = jb;
        for (; j + 8 <= je; j += 8) {
            int2 p[8];
#pragma unroll
            for (int t = 0; t < 8; ++t) p[t] = epair[j + t];
            float f[8];
#pragma unroll
            for (int t = 0; t < 8; ++t) f[t] = feat_row(ue, ie, p[t].x)[lane];
#pragma unroll
            for (int t = 0; t < 8; ++t) {
                const float v = __int_as_float(p[t].y);
                acc1 = fmaf(v, f[t], acc1);
                acc2 = fmaf(v * f[t], f[t], acc2);
            }
        }
        for (; j + 4 <= je; j += 4) {
            int2 p[4];
#pragma unroll
            for (int t = 0; t < 4; ++t) p[t] = epair[j + t];
            float f[4];
#pragma unroll
            for (int t = 0; t < 4; ++t) f[t] = feat_row(ue, ie, p[t].x)[lane];
#pragma unroll
            for (int t = 0; t < 4; ++t) {
                const float v = __int_as_float(p[t].y);
                acc1 = fmaf(v, f[t], acc1);
                acc2 = fmaf(v * f[t], f[t], acc2);
            }
        }
        for (; j < je; ++j) {
            const int2 p = epair[j];
            const float f = feat_row(ue, ie, p.x)[lane];
            const float v = __int_as_float(p.y);
            acc1 = fmaf(v, f, acc1);
            acc2 = fmaf(v * f, f, acc2);
        }
        lx [(size_t)r * DD + lane] = acc1 + feat_row(ue, ie, r)[lane];
        lx2[(size_t)r * DD + lane] = acc2;
    }
}

// ---- GCN transform, zero-LDS, weights in VGPRs -----------------------------
// h = leaky_relu(a1@Wg1 + a2@Wg2 + bg1 + bg2).
// Activation rows are read with UNIFORM-ADDRESS VECTOR loads (no
// readfirstlane on the row index, so the compiler emits global_load_dwordx4
// which pipeline under vmcnt, instead of serial s_load chains).

__global__ __launch_bounds__(256) void gcn_h_kernel(
    const float* __restrict__ a1, const float* __restrict__ a2,
    const float* __restrict__ Wg1, const float* __restrict__ bg1,
    const float* __restrict__ Wg2, const float* __restrict__ bg2,
    float* __restrict__ h) {
    const int lane = threadIdx.x & 63;
    float w1[DD], w2[DD];
#pragma unroll
    for (int k = 0; k < DD; ++k) {
        w1[k] = Wg1[k * DD + lane];
        w2[k] = Wg2[k * DD + lane];
    }
    const float bias = bg1[lane] + bg2[lane];
    const int wv = (int)((blockIdx.x * blockDim.x + threadIdx.x) >> 6);
    const int nw = (int)((gridDim.x * blockDim.x) >> 6);
    for (int r = wv; r < NNODE; r += nw) {
        const float* ar = a1 + (size_t)r * DD;
        const float* br = a2 + (size_t)r * DD;
        float o0 = bias, o1 = 0.f, o2 = 0.f, o3 = 0.f;
#pragma unroll
        for (int k4 = 0; k4 < DD / 4; ++k4) {
            const float4 qa = *(const float4*)(ar + 4 * k4);
            const float4 qb = *(const float4*)(br + 4 * k4);
            o0 = fmaf(qa.x, w1[4 * k4 + 0], o0);
            o1 = fmaf(qa.y, w1[4 * k4 + 1], o1);
            o0 = fmaf(qa.z, w1[4 * k4 + 2], o0);
            o1 = fmaf(qa.w, w1[4 * k4 + 3], o1);
            o2 = fmaf(qb.x, w2[4 * k4 + 0], o2);
            o3 = fmaf(qb.y, w2[4 * k4 + 1], o3);
            o2 = fmaf(qb.z, w2[4 * k4 + 2], o2);
            o3 = fmaf(qb.w, w2[4 * k4 + 3], o3);
        }
        const float x = (o0 + o1) + (o2 + o3);
        h[(size_t)r * DD + lane] = (x > 0.f) ? x : 0.01f * x;
    }
}

// ---- Per-node MLP layer-1 partial, zero-LDS, same load pattern -------------
// user: part[n] = f@W1[0:64]   + h@W1[64:128]  + b1
// item: part[n] = f@W1[128:192]+ h@W1[192:256]

__global__ __launch_bounds__(256) void part_kernel(
    const float* __restrict__ ue, const float* __restrict__ ie,
    const float* __restrict__ h,
    const float* __restrict__ W1, const float* __restrict__ b1,
    float* __restrict__ part) {
    const bool is_user = blockIdx.x < NB_U2;
    const float* Wh = W1 + (is_user ? 0 : 2 * DD * DD);
    const int lane = threadIdx.x & 63;
    float wa[DD], wb[DD];
#pragma unroll
    for (int k = 0; k < DD; ++k) {
        wa[k] = Wh[k * DD + lane];
        wb[k] = Wh[(DD + k) * DD + lane];
    }
    const float bias = is_user ? b1[lane] : 0.f;
    const float* fb  = is_user ? ue : ie;
    const int count  = is_user ? USER_NUM : ITEM_NUM;
    const int nbase  = is_user ? 0 : USER_NUM;
    const int nwav   = (is_user ? NB_U2 : NB_I2) * 4;
    const int lw = (is_user ? blockIdx.x : blockIdx.x - NB_U2) * 4
                   + (int)(threadIdx.x >> 6);
    for (int idx = lw; idx < count; idx += nwav) {
        const float* fr = fb + (size_t)idx * DD;
        const float* hr = h + (size_t)(nbase + idx) * DD;
        float p0 = bias, p1 = 0.f, p2 = 0.f, p3 = 0.f;
#pragma unroll
        for (int k4 = 0; k4 < DD / 4; ++k4) {
            const float4 qf = *(const float4*)(fr + 4 * k4);
            const float4 qh = *(const float4*)(hr + 4 * k4);
            p0 = fmaf(qf.x, wa[4 * k4 + 0], p0);
            p1 = fmaf(qf.y, wa[4 * k4 + 1], p1);
            p0 = fmaf(qf.z, wa[4 * k4 + 2], p0);
            p1 = fmaf(qf.w, wa[4 * k4 + 3], p1);
            p2 = fmaf(qh.x, wb[4 * k4 + 0], p2);
            p3 = fmaf(qh.y, wb[4 * k4 + 1], p3);
            p2 = fmaf(qh.z, wb[4 * k4 + 2], p2);
            p3 = fmaf(qh.w, wb[4 * k4 + 3], p3);
        }
        part[(size_t)(nbase + idx) * DD + lane] = (p0 + p1) + (p2 + p3);
    }
}

// ---- Per-sample MLP: o1 = relu(part_u + part_i); layers 2,3 ----------------

__global__ __launch_bounds__(256) void mlp_kernel(
    const float* __restrict__ part,
    const float* __restrict__ W2, const float* __restrict__ b2,
    const float* __restrict__ W3, const float* __restrict__ b3,
    const int* __restrict__ uid, const int* __restrict__ iid,
    float* __restrict__ out, int B) {
    __shared__ float sW2[DD * 32];
    __shared__ float sW3[32];
    for (int i = threadIdx.x; i < DD * 32; i += 256) sW2[i] = W2[i];
    if (threadIdx.x < 32) sW3[threadIdx.x] = W3[threadIdx.x];
    __syncthreads();
    const int lane = threadIdx.x & 63;
    const int wave = (int)((blockIdx.x * blockDim.x + threadIdx.x) >> 6);
    const int nw   = (int)((gridDim.x * blockDim.x) >> 6);
    const float bias2 = b2[lane & 31];
    const float w3v   = sW3[lane & 31];
    const float bias3 = b3[0];
    for (int s = wave; s < B; s += nw) {
        const int u  = uid[s];
        const int it = iid[s];
        const float pu = part[(size_t)u * DD + lane];
        const float pi = part[(size_t)(USER_NUM + it) * DD + lane];
        const float x  = pu + pi;
        const float o1 = (x > 0.f) ? x : 0.f;
        float acc_a = bias2, acc_b = 0.f;
#pragma unroll
        for (int k = 0; k < DD; k += 2) {
            acc_a = fmaf(__shfl(o1, k),     sW2[k * 32 + (lane & 31)],       acc_a);
            acc_b = fmaf(__shfl(o1, k + 1), sW2[(k + 1) * 32 + (lane & 31)], acc_b);
        }
        const float a2 = acc_a + acc_b;
        const float o2 = (a2 > 0.f) ? a2 : 0.f;
        float p = o2 * w3v;
        p += __shfl_xor(p, 1);
        p += __shfl_xor(p, 2);
        p += __shfl_xor(p, 4);
        p += __shfl_xor(p, 8);
        p += __shfl_xor(p, 16);
        if (lane == 0) out[s] = p + bias3;
    }
}

extern "C" void kernel_launch(void* const* d_in, const int* in_sizes, int n_in,
                              void* d_out, int out_size, void* d_ws, size_t ws_size,
                              hipStream_t stream) {
    const float* ue   = (const float*)d_in[0];
    const float* ie   = (const float*)d_in[1];
    const int*   erow = (const int*)d_in[2];
    const int*   ecol = (const int*)d_in[3];
    const float* evalp= (const float*)d_in[4];
    const float* Wg1  = (const float*)d_in[5];
    const float* bg1  = (const float*)d_in[6];
    const float* Wg2  = (const float*)d_in[7];
    const float* bg2  = (const float*)d_in[8];
    const float* W1   = (const float*)d_in[9];
    const float* b1   = (const float*)d_in[10];
    const float* W2   = (const float*)d_in[11];
    const float* b2   = (const float*)d_in[12];
    const float* W3   = (const float*)d_in[13];
    const float* b3   = (const float*)d_in[14];
    const int*   uid  = (const int*)d_in[15];
    const int*   iid  = (const int*)d_in[16];
    float* out = (float*)d_out;

    const int E = in_sizes[2];
    const int B = in_sizes[15];

    // workspace (53.76 MB total):
    //   [lx 17.92MB][lx2 17.92MB][epair 16MB][cnt .28][cursor .28][base .28]
    // h (17.92MB) OVERLAYS [epair..base] — all dead once spmm finishes.
    // part reuses lx2 (dead after gcn_h).
    char* ws = (char*)d_ws;
    const size_t nd = (size_t)NNODE * DD;
    float* lx    = (float*)ws;
    float* lx2   = lx + nd;
    float* part  = lx2;                                     // alias (lx2 dead)
    char*  tail  = ws + 2 * nd * sizeof(float);
    int2*  epair = (int2*)tail;
    int*   cnt   = (int*)(tail + (size_t)E * sizeof(int2));
    int*   cursor= cnt + NNODE;
    int*   base  = cursor + NNODE;                          // NNODE+1 ints
    float* h     = (float*)tail;                            // overlays epair..base

    hipMemsetAsync(cnt, 0, NNODE * sizeof(int), stream);

    hist_kernel<<<2048, 256, 0, stream>>>(erow, cnt, E);
    scan_kernel<<<1, SCAN_T, 0, stream>>>(cnt, base);
    hipMemcpyAsync(cursor, base, NNODE * sizeof(int), hipMemcpyDeviceToDevice, stream);
    scatter_kernel<<<8 * NSTRIPE, 256, 0, stream>>>(erow, ecol, evalp, cursor, epair, E);
    spmm_kernel<<<4096, 256, 0, stream>>>(ue, ie, epair, base, lx, lx2);
    gcn_h_kernel<<<1024, 256, 0, stream>>>(lx, lx2, Wg1, bg1, Wg2, bg2, h);
    part_kernel<<<NB_U2 + NB_I2, 256, 0, stream>>>(ue, ie, h, W1, b1, part);
    mlp_kernel<<<1024, 256, 0, stream>>>(part, W2, b2, W3, b3, uid, iid, out, B);
}

// Round 8
// 555.698 us; speedup vs baseline: 1.0718x; 1.0614x over previous
//
#include <hip/hip_runtime.h>
#include <hip/hip_bf16.h>

#define USER_NUM 50000
#define ITEM_NUM 20000
#define NNODE    70000
#define DD       64
#define SCAN_T   1024
#define NSTRIPE  256   // scatter: stripes per group; grid = 8*NSTRIPE blocks

__device__ __forceinline__ const float* feat_row(const float* __restrict__ ue,
                                                 const float* __restrict__ ie, int n) {
    return (n < USER_NUM) ? (ue + (size_t)n * DD)
                          : (ie + (size_t)(n - USER_NUM) * DD);
}

// ---- CSR build: histogram -> block scan -> grouped scatter -----------------

__global__ __launch_bounds__(256) void hist_kernel(const int* __restrict__ erow,
                                                   int* __restrict__ cnt, int E) {
    const int stride = gridDim.x * blockDim.x;
    for (int e = blockIdx.x * blockDim.x + threadIdx.x; e < E; e += stride)
        atomicAdd(&cnt[erow[e]], 1);
}

__global__ __launch_bounds__(SCAN_T) void scan_kernel(const int* __restrict__ cnt,
                                                      int* __restrict__ base) {
    __shared__ int s[SCAN_T];
    const int t = threadIdx.x;
    const int CH = (NNODE + SCAN_T - 1) / SCAN_T;   // 69
    const int lo = t * CH;
    const int hi = min(lo + CH, NNODE);
    int sum = 0;
    for (int i = lo; i < hi; ++i) sum += cnt[i];
    s[t] = sum;
    __syncthreads();
    for (int off = 1; off < SCAN_T; off <<= 1) {
        int v = s[t];
        int u = (t >= off) ? s[t - off] : 0;
        __syncthreads();
        s[t] = v + u;
        __syncthreads();
    }
    int running = s[t] - sum;
    for (int i = lo; i < hi; ++i) {
        base[i] = running;
        running += cnt[i];
    }
    if (t == SCAN_T - 1) base[NNODE] = s[SCAN_T - 1];
}

// Destination-grouped scatter (round-5 notes). Perf heuristic only.
__global__ __launch_bounds__(256) void scatter_kernel(
    const int* __restrict__ erow, const int* __restrict__ ecol,
    const float* __restrict__ eval,
    int* __restrict__ cursor, int2* __restrict__ epair, int E) {
    const int g    = blockIdx.x & 7;
    const int rank = blockIdx.x >> 3;                 // 0..NSTRIPE-1
    const int CH   = (E + NSTRIPE - 1) / NSTRIPE;
    const int lo   = rank * CH;
    const int hi   = min(lo + CH, E);
    for (int e = lo + (int)threadIdx.x; e < hi; e += 256) {
        const int r = erow[e];
        const int gr = (r * 8) / NNODE;               // const div -> magic mul
        if (gr == g) {
            const int pos = atomicAdd(&cursor[r], 1);
            epair[pos] = make_int2(ecol[e], __float_as_int(eval[e]));
        }
    }
}

// ---- SpMM, gather form, scalarized edge stream, 8 gathers in flight --------
// Stores a1 = lx + f (self term folded) and a2 = lx2.

__global__ __launch_bounds__(256) void spmm_kernel(
    const float* __restrict__ ue, const float* __restrict__ ie,
    const int2* __restrict__ epair, const int* __restrict__ base,
    float* __restrict__ lx, float* __restrict__ lx2) {
    const int lane = threadIdx.x & 63;
    int wv = (int)((blockIdx.x * blockDim.x + threadIdx.x) >> 6);
    wv = __builtin_amdgcn_readfirstlane(wv);
    const int nw = (int)((gridDim.x * blockDim.x) >> 6);
    for (int r = wv; r < NNODE; r += nw) {
        const int jb = base[r];
        const int je = base[r + 1];
        float acc1 = 0.f, acc2 = 0.f;
        int j = jb;
        for (; j + 8 <= je; j += 8) {
            int2 p[8];
#pragma unroll
            for (int t = 0; t < 8; ++t) p[t] = epair[j + t];
            float f[8];
#pragma unroll
            for (int t = 0; t < 8; ++t) f[t] = feat_row(ue, ie, p[t].x)[lane];
#pragma unroll
            for (int t = 0; t < 8; ++t) {
                const float v = __int_as_float(p[t].y);
                acc1 = fmaf(v, f[t], acc1);
                acc2 = fmaf(v * f[t], f[t], acc2);
            }
        }
        for (; j + 4 <= je; j += 4) {
            int2 p[4];
#pragma unroll
            for (int t = 0; t < 4; ++t) p[t] = epair[j + t];
            float f[4];
#pragma unroll
            for (int t = 0; t < 4; ++t) f[t] = feat_row(ue, ie, p[t].x)[lane];
#pragma unroll
            for (int t = 0; t < 4; ++t) {
                const float v = __int_as_float(p[t].y);
                acc1 = fmaf(v, f[t], acc1);
                acc2 = fmaf(v * f[t], f[t], acc2);
            }
        }
        for (; j < je; ++j) {
            const int2 p = epair[j];
            const float f = feat_row(ue, ie, p.x)[lane];
            const float v = __int_as_float(p.y);
            acc1 = fmaf(v, f, acc1);
            acc2 = fmaf(v * f, f, acc2);
        }
        lx [(size_t)r * DD + lane] = acc1 + feat_row(ue, ie, r)[lane];
        lx2[(size_t)r * DD + lane] = acc2;
    }
}

// ---- Tiled transform: out[n] = act(xa[n]@Wa + xb[n]@Wb + bias) -------------
// 64-row tile per block. 4 waves: wave = (rhalf, khalf) split; each wave pins
// only 64 weight VGPRs (2 matrices x 32 K-slice), activations staged in LDS
// coalesced and consumed as uniform-address ds_read_b128 broadcasts (HW
// broadcast, conflict-free). Partials combined via LDS atomicAdd (ds_add_f32).
// LRELU: leaky-relu epilogue (GCN); else identity (MLP layer-1 partial).

template <bool LRELU>
__global__ __launch_bounds__(256) void xform_kernel(
    const float* __restrict__ xa, const float* __restrict__ xb,
    const float* __restrict__ Wa, const float* __restrict__ Wb,
    const float* __restrict__ bias1, const float* __restrict__ bias2,
    float* __restrict__ out, int count) {
    __shared__ float sXa[64 * DD];
    __shared__ float sXb[64 * DD];
    __shared__ float sP [64 * DD];
    const int t     = threadIdx.x;
    const int lane  = t & 63;
    const int w     = t >> 6;
    const int khalf = (w & 1) * 32;
    const int rhalf = (w >> 1) * 32;

    float wva[32], wvb[32];
#pragma unroll
    for (int k = 0; k < 32; ++k) {
        wva[k] = Wa[(khalf + k) * DD + lane];
        wvb[k] = Wb[(khalf + k) * DD + lane];
    }

    const int base = blockIdx.x * 64;
    const float4* xav = (const float4*)xa;
    const float4* xbv = (const float4*)xb;
    float4* sXav = (float4*)sXa;
    float4* sXbv = (float4*)sXb;
    float4* sPv  = (float4*)sP;
    // zero partials + stage tile (rows clamped; OOB rows computed, not stored)
#pragma unroll
    for (int i = 0; i < 4; ++i) {
        const int f4  = t + 256 * i;
        const int row = f4 >> 4;
        const int c   = f4 & 15;
        const int g   = min(base + row, count - 1);
        sXav[f4] = xav[(size_t)g * 16 + c];
        sXbv[f4] = xbv[(size_t)g * 16 + c];
        sPv[f4]  = make_float4(0.f, 0.f, 0.f, 0.f);
    }
    __syncthreads();

#pragma unroll 2
    for (int r = 0; r < 32; ++r) {
        const int row = rhalf + r;
        const float* ra = &sXa[row * DD + khalf];
        const float* rb = &sXb[row * DD + khalf];
        float o0 = 0.f, o1 = 0.f, o2 = 0.f, o3 = 0.f;
#pragma unroll
        for (int q = 0; q < 8; ++q) {
            const float4 qa = *(const float4*)(ra + 4 * q);
            const float4 qb = *(const float4*)(rb + 4 * q);
            o0 = fmaf(qa.x, wva[4 * q + 0], o0);
            o1 = fmaf(qa.y, wva[4 * q + 1], o1);
            o0 = fmaf(qa.z, wva[4 * q + 2], o0);
            o1 = fmaf(qa.w, wva[4 * q + 3], o1);
            o2 = fmaf(qb.x, wvb[4 * q + 0], o2);
            o3 = fmaf(qb.y, wvb[4 * q + 1], o3);
            o2 = fmaf(qb.z, wvb[4 * q + 2], o2);
            o3 = fmaf(qb.w, wvb[4 * q + 3], o3);
        }
        atomicAdd(&sP[row * DD + lane], (o0 + o1) + (o2 + o3));
    }
    __syncthreads();

    float4* outv = (float4*)out;
#pragma unroll
    for (int i = 0; i < 4; ++i) {
        const int f4  = t + 256 * i;
        const int row = f4 >> 4;
        const int c   = f4 & 15;
        const int g   = base + row;
        float4 v = sPv[f4];
        if (bias1) {
            const float4 b = ((const float4*)bias1)[c];
            v.x += b.x; v.y += b.y; v.z += b.z; v.w += b.w;
        }
        if (bias2) {
            const float4 b = ((const float4*)bias2)[c];
            v.x += b.x; v.y += b.y; v.z += b.z; v.w += b.w;
        }
        if (LRELU) {
            v.x = (v.x > 0.f) ? v.x : 0.01f * v.x;
            v.y = (v.y > 0.f) ? v.y : 0.01f * v.y;
            v.z = (v.z > 0.f) ? v.z : 0.01f * v.z;
            v.w = (v.w > 0.f) ? v.w : 0.01f * v.w;
        }
        if (g < count) outv[(size_t)g * 16 + c] = v;
    }
}

// ---- Per-sample MLP: o1 = relu(part_u + part_i); layers 2,3 ----------------

__global__ __launch_bounds__(256) void mlp_kernel(
    const float* __restrict__ part,
    const float* __restrict__ W2, const float* __restrict__ b2,
    const float* __restrict__ W3, const float* __restrict__ b3,
    const int* __restrict__ uid, const int* __restrict__ iid,
    float* __restrict__ out, int B) {
    __shared__ float sW2[DD * 32];
    __shared__ float sW3[32];
    for (int i = threadIdx.x; i < DD * 32; i += 256) sW2[i] = W2[i];
    if (threadIdx.x < 32) sW3[threadIdx.x] = W3[threadIdx.x];
    __syncthreads();
    const int lane = threadIdx.x & 63;
    const int wave = (int)((blockIdx.x * blockDim.x + threadIdx.x) >> 6);
    const int nw   = (int)((gridDim.x * blockDim.x) >> 6);
    const float bias2 = b2[lane & 31];
    const float w3v   = sW3[lane & 31];
    const float bias3 = b3[0];
    for (int s = wave; s < B; s += nw) {
        const int u  = uid[s];
        const int it = iid[s];
        const float pu = part[(size_t)u * DD + lane];
        const float pi = part[(size_t)(USER_NUM + it) * DD + lane];
        const float x  = pu + pi;
        const float o1 = (x > 0.f) ? x : 0.f;
        float acc_a = bias2, acc_b = 0.f;
#pragma unroll
        for (int k = 0; k < DD; k += 2) {
            acc_a = fmaf(__shfl(o1, k),     sW2[k * 32 + (lane & 31)],       acc_a);
            acc_b = fmaf(__shfl(o1, k + 1), sW2[(k + 1) * 32 + (lane & 31)], acc_b);
        }
        const float a2 = acc_a + acc_b;
        const float o2 = (a2 > 0.f) ? a2 : 0.f;
        float p = o2 * w3v;
        p += __shfl_xor(p, 1);
        p += __shfl_xor(p, 2);
        p += __shfl_xor(p, 4);
        p += __shfl_xor(p, 8);
        p += __shfl_xor(p, 16);
        if (lane == 0) out[s] = p + bias3;
    }
}

extern "C" void kernel_launch(void* const* d_in, const int* in_sizes, int n_in,
                              void* d_out, int out_size, void* d_ws, size_t ws_size,
                              hipStream_t stream) {
    const float* ue   = (const float*)d_in[0];
    const float* ie   = (const float*)d_in[1];
    const int*   erow = (const int*)d_in[2];
    const int*   ecol = (const int*)d_in[3];
    const float* evalp= (const float*)d_in[4];
    const float* Wg1  = (const float*)d_in[5];
    const float* bg1  = (const float*)d_in[6];
    const float* Wg2  = (const float*)d_in[7];
    const float* bg2  = (const float*)d_in[8];
    const float* W1   = (const float*)d_in[9];
    const float* b1   = (const float*)d_in[10];
    const float* W2   = (const float*)d_in[11];
    const float* b2   = (const float*)d_in[12];
    const float* W3   = (const float*)d_in[13];
    const float* b3   = (const float*)d_in[14];
    const int*   uid  = (const int*)d_in[15];
    const int*   iid  = (const int*)d_in[16];
    float* out = (float*)d_out;

    const int E = in_sizes[2];
    const int B = in_sizes[15];

    // workspace (53.76 MB total):
    //   [lx 17.92MB][lx2 17.92MB][epair 16MB][cnt .28][cursor .28][base .28]
    // h (17.92MB) OVERLAYS [epair..base] — all dead once spmm finishes.
    // part reuses lx2 (dead after gcn transform).
    char* ws = (char*)d_ws;
    const size_t nd = (size_t)NNODE * DD;
    float* lx    = (float*)ws;
    float* lx2   = lx + nd;
    float* part  = lx2;                                     // alias (lx2 dead)
    char*  tail  = ws + 2 * nd * sizeof(float);
    int2*  epair = (int2*)tail;
    int*   cnt   = (int*)(tail + (size_t)E * sizeof(int2));
    int*   cursor= cnt + NNODE;
    int*   base  = cursor + NNODE;                          // NNODE+1 ints
    float* h     = (float*)tail;                            // overlays epair..base

    hipMemsetAsync(cnt, 0, NNODE * sizeof(int), stream);

    hist_kernel<<<2048, 256, 0, stream>>>(erow, cnt, E);
    scan_kernel<<<1, SCAN_T, 0, stream>>>(cnt, base);
    hipMemcpyAsync(cursor, base, NNODE * sizeof(int), hipMemcpyDeviceToDevice, stream);
    scatter_kernel<<<8 * NSTRIPE, 256, 0, stream>>>(erow, ecol, evalp, cursor, epair, E);
    spmm_kernel<<<4096, 256, 0, stream>>>(ue, ie, epair, base, lx, lx2);

    // h = leaky_relu(a1@Wg1 + a2@Wg2 + bg1 + bg2)
    xform_kernel<true><<<(NNODE + 63) / 64, 256, 0, stream>>>(
        lx, lx2, Wg1, Wg2, bg1, bg2, h, NNODE);
    // part (layer-1 partial): users then items
    xform_kernel<false><<<(USER_NUM + 63) / 64, 256, 0, stream>>>(
        ue, h, W1, W1 + DD * DD, b1, nullptr, part, USER_NUM);
    xform_kernel<false><<<(ITEM_NUM + 63) / 64, 256, 0, stream>>>(
        ie, h + (size_t)USER_NUM * DD, W1 + 2 * DD * DD, W1 + 3 * DD * DD,
        nullptr, nullptr, part + (size_t)USER_NUM * DD, ITEM_NUM);

    mlp_kernel<<<1024, 256, 0, stream>>>(part, W2, b2, W3, b3, uid, iid, out, B);
}

// Round 9
// 452.161 us; speedup vs baseline: 1.3173x; 1.2290x over previous
//
#include <hip/hip_runtime.h>
#include <hip/hip_bf16.h>

#define USER_NUM 50000
#define ITEM_NUM 20000
#define NNODE    70000
#define DD       64
#define NSTRIPE  256   // scatter: stripes per group; grid = 8*NSTRIPE blocks
#define CHUNK    1024
#define NCHUNK   ((NNODE + CHUNK - 1) / CHUNK)   // 69

__device__ __forceinline__ const float* feat_row(const float* __restrict__ ue,
                                                 const float* __restrict__ ie, int n) {
    return (n < USER_NUM) ? (ue + (size_t)n * DD)
                          : (ie + (size_t)(n - USER_NUM) * DD);
}

// ---- CSR build: histogram -> 3-phase parallel scan -> grouped scatter ------

__global__ __launch_bounds__(256) void hist_kernel(const int* __restrict__ erow,
                                                   int* __restrict__ cnt, int E) {
    const int stride = gridDim.x * blockDim.x;
    for (int e = blockIdx.x * blockDim.x + threadIdx.x; e < E; e += stride)
        atomicAdd(&cnt[erow[e]], 1);
}

// Phase 1: per-chunk sums (coalesced strided loads + wave/block reduce).
__global__ __launch_bounds__(256) void chunksum_kernel(const int* __restrict__ cnt,
                                                       int* __restrict__ csum) {
    __shared__ int red[4];
    const int c = blockIdx.x;
    const int t = threadIdx.x;
    int s = 0;
#pragma unroll
    for (int i = 0; i < 4; ++i) {
        const int idx = c * CHUNK + t + 256 * i;
        s += (idx < NNODE) ? cnt[idx] : 0;
    }
#pragma unroll
    for (int off = 32; off; off >>= 1) s += __shfl_down(s, off);
    if ((t & 63) == 0) red[t >> 6] = s;
    __syncthreads();
    if (t == 0) csum[c] = red[0] + red[1] + red[2] + red[3];
}

// Phase 2: exclusive scan of the 69 chunk sums (one tiny block).
__global__ __launch_bounds__(128) void scan_small_kernel(const int* __restrict__ csum,
                                                         int* __restrict__ coff) {
    __shared__ int s[128];
    const int t = threadIdx.x;
    const int v = (t < NCHUNK) ? csum[t] : 0;
    s[t] = v;
    __syncthreads();
    for (int off = 1; off < 128; off <<= 1) {
        const int val = s[t];
        const int add = (t >= off) ? s[t - off] : 0;
        __syncthreads();
        s[t] = val + add;
        __syncthreads();
    }
    if (t < NCHUNK) coff[t] = s[t] - v;
}

// Phase 3: per-chunk fill: dwordx4 loads, block scan, write base AND cursor.
__global__ __launch_bounds__(256) void fill_kernel(const int* __restrict__ cnt,
                                                   const int* __restrict__ coff,
                                                   int* __restrict__ base,
                                                   int* __restrict__ cursor) {
    __shared__ int sp[256];
    const int c  = blockIdx.x;
    const int t  = threadIdx.x;
    const int g0 = c * CHUNK + t * 4;
    int v[4];
#pragma unroll
    for (int i = 0; i < 4; ++i) v[i] = (g0 + i < NNODE) ? cnt[g0 + i] : 0;
    const int s = ((v[0] + v[1]) + (v[2] + v[3]));
    sp[t] = s;
    __syncthreads();
    for (int off = 1; off < 256; off <<= 1) {
        const int val = sp[t];
        const int add = (t >= off) ? sp[t - off] : 0;
        __syncthreads();
        sp[t] = val + add;
        __syncthreads();
    }
    int run = coff[c] + sp[t] - s;          // exclusive prefix for elem g0
#pragma unroll
    for (int i = 0; i < 4; ++i) {
        const int g = g0 + i;
        if (g < NNODE) {
            base[g]   = run;
            cursor[g] = run;
            run += v[i];
        } else if (g == NNODE) {
            base[g] = run;                  // == E
        }
    }
}

// Destination-grouped scatter (round-5 notes). Perf heuristic only.
__global__ __launch_bounds__(256) void scatter_kernel(
    const int* __restrict__ erow, const int* __restrict__ ecol,
    const float* __restrict__ eval,
    int* __restrict__ cursor, int2* __restrict__ epair, int E) {
    const int g    = blockIdx.x & 7;
    const int rank = blockIdx.x >> 3;                 // 0..NSTRIPE-1
    const int CH   = (E + NSTRIPE - 1) / NSTRIPE;
    const int lo   = rank * CH;
    const int hi   = min(lo + CH, E);
    for (int e = lo + (int)threadIdx.x; e < hi; e += 256) {
        const int r = erow[e];
        const int gr = (r * 8) / NNODE;               // const div -> magic mul
        if (gr == g) {
            const int pos = atomicAdd(&cursor[r], 1);
            epair[pos] = make_int2(ecol[e], __float_as_int(eval[e]));
        }
    }
}

// ---- SpMM, gather form, scalarized edge stream, 8 gathers in flight --------
// Stores a1 = lx + f (self term folded) and a2 = lx2.

__global__ __launch_bounds__(256) void spmm_kernel(
    const float* __restrict__ ue, const float* __restrict__ ie,
    const int2* __restrict__ epair, const int* __restrict__ base,
    float* __restrict__ lx, float* __restrict__ lx2) {
    const int lane = threadIdx.x & 63;
    int wv = (int)((blockIdx.x * blockDim.x + threadIdx.x) >> 6);
    wv = __builtin_amdgcn_readfirstlane(wv);
    const int nw = (int)((gridDim.x * blockDim.x) >> 6);
    for (int r = wv; r < NNODE; r += nw) {
        const int jb = base[r];
        const int je = base[r + 1];
        float acc1 = 0.f, acc2 = 0.f;
        int j = jb;
        for (; j + 8 <= je; j += 8) {
            int2 p[8];
#pragma unroll
            for (int t = 0; t < 8; ++t) p[t] = epair[j + t];
            float f[8];
#pragma unroll
            for (int t = 0; t < 8; ++t) f[t] = feat_row(ue, ie, p[t].x)[lane];
#pragma unroll
            for (int t = 0; t < 8; ++t) {
                const float v = __int_as_float(p[t].y);
                acc1 = fmaf(v, f[t], acc1);
                acc2 = fmaf(v * f[t], f[t], acc2);
            }
        }
        for (; j + 4 <= je; j += 4) {
            int2 p[4];
#pragma unroll
            for (int t = 0; t < 4; ++t) p[t] = epair[j + t];
            float f[4];
#pragma unroll
            for (int t = 0; t < 4; ++t) f[t] = feat_row(ue, ie, p[t].x)[lane];
#pragma unroll
            for (int t = 0; t < 4; ++t) {
                const float v = __int_as_float(p[t].y);
                acc1 = fmaf(v, f[t], acc1);
                acc2 = fmaf(v * f[t], f[t], acc2);
            }
        }
        for (; j < je; ++j) {
            const int2 p = epair[j];
            const float f = feat_row(ue, ie, p.x)[lane];
            const float v = __int_as_float(p.y);
            acc1 = fmaf(v, f, acc1);
            acc2 = fmaf(v * f, f, acc2);
        }
        lx [(size_t)r * DD + lane] = acc1 + feat_row(ue, ie, r)[lane];
        lx2[(size_t)r * DD + lane] = acc2;
    }
}

// ---- Tiled transform: out[n] = act(xa[n]@Wa + xb[n]@Wb + bias) -------------
// (see round-7 notes: K-split waves, LDS broadcast reads, ds_add partials)

template <bool LRELU>
__global__ __launch_bounds__(256) void xform_kernel(
    const float* __restrict__ xa, const float* __restrict__ xb,
    const float* __restrict__ Wa, const float* __restrict__ Wb,
    const float* __restrict__ bias1, const float* __restrict__ bias2,
    float* __restrict__ out, int count) {
    __shared__ float sXa[64 * DD];
    __shared__ float sXb[64 * DD];
    __shared__ float sP [64 * DD];
    const int t     = threadIdx.x;
    const int lane  = t & 63;
    const int w     = t >> 6;
    const int khalf = (w & 1) * 32;
    const int rhalf = (w >> 1) * 32;

    float wva[32], wvb[32];
#pragma unroll
    for (int k = 0; k < 32; ++k) {
        wva[k] = Wa[(khalf + k) * DD + lane];
        wvb[k] = Wb[(khalf + k) * DD + lane];
    }

    const int base = blockIdx.x * 64;
    const float4* xav = (const float4*)xa;
    const float4* xbv = (const float4*)xb;
    float4* sXav = (float4*)sXa;
    float4* sXbv = (float4*)sXb;
    float4* sPv  = (float4*)sP;
#pragma unroll
    for (int i = 0; i < 4; ++i) {
        const int f4  = t + 256 * i;
        const int row = f4 >> 4;
        const int c   = f4 & 15;
        const int g   = min(base + row, count - 1);
        sXav[f4] = xav[(size_t)g * 16 + c];
        sXbv[f4] = xbv[(size_t)g * 16 + c];
        sPv[f4]  = make_float4(0.f, 0.f, 0.f, 0.f);
    }
    __syncthreads();

#pragma unroll 2
    for (int r = 0; r < 32; ++r) {
        const int row = rhalf + r;
        const float* ra = &sXa[row * DD + khalf];
        const float* rb = &sXb[row * DD + khalf];
        float o0 = 0.f, o1 = 0.f, o2 = 0.f, o3 = 0.f;
#pragma unroll
        for (int q = 0; q < 8; ++q) {
            const float4 qa = *(const float4*)(ra + 4 * q);
            const float4 qb = *(const float4*)(rb + 4 * q);
            o0 = fmaf(qa.x, wva[4 * q + 0], o0);
            o1 = fmaf(qa.y, wva[4 * q + 1], o1);
            o0 = fmaf(qa.z, wva[4 * q + 2], o0);
            o1 = fmaf(qa.w, wva[4 * q + 3], o1);
            o2 = fmaf(qb.x, wvb[4 * q + 0], o2);
            o3 = fmaf(qb.y, wvb[4 * q + 1], o3);
            o2 = fmaf(qb.z, wvb[4 * q + 2], o2);
            o3 = fmaf(qb.w, wvb[4 * q + 3], o3);
        }
        atomicAdd(&sP[row * DD + lane], (o0 + o1) + (o2 + o3));
    }
    __syncthreads();

    float4* outv = (float4*)out;
#pragma unroll
    for (int i = 0; i < 4; ++i) {
        const int f4  = t + 256 * i;
        const int row = f4 >> 4;
        const int c   = f4 & 15;
        const int g   = base + row;
        float4 v = sPv[f4];
        if (bias1) {
            const float4 b = ((const float4*)bias1)[c];
            v.x += b.x; v.y += b.y; v.z += b.z; v.w += b.w;
        }
        if (bias2) {
            const float4 b = ((const float4*)bias2)[c];
            v.x += b.x; v.y += b.y; v.z += b.z; v.w += b.w;
        }
        if (LRELU) {
            v.x = (v.x > 0.f) ? v.x : 0.01f * v.x;
            v.y = (v.y > 0.f) ? v.y : 0.01f * v.y;
            v.z = (v.z > 0.f) ? v.z : 0.01f * v.z;
            v.w = (v.w > 0.f) ? v.w : 0.01f * v.w;
        }
        if (g < count) outv[(size_t)g * 16 + c] = v;
    }
}

// ---- Per-sample MLP: o1 = relu(part_u + part_i); layers 2,3 ----------------

__global__ __launch_bounds__(256) void mlp_kernel(
    const float* __restrict__ part,
    const float* __restrict__ W2, const float* __restrict__ b2,
    const float* __restrict__ W3, const float* __restrict__ b3,
    const int* __restrict__ uid, const int* __restrict__ iid,
    float* __restrict__ out, int B) {
    __shared__ float sW2[DD * 32];
    __shared__ float sW3[32];
    for (int i = threadIdx.x; i < DD * 32; i += 256) sW2[i] = W2[i];
    if (threadIdx.x < 32) sW3[threadIdx.x] = W3[threadIdx.x];
    __syncthreads();
    const int lane = threadIdx.x & 63;
    const int wave = (int)((blockIdx.x * blockDim.x + threadIdx.x) >> 6);
    const int nw   = (int)((gridDim.x * blockDim.x) >> 6);
    const float bias2 = b2[lane & 31];
    const float w3v   = sW3[lane & 31];
    const float bias3 = b3[0];
    for (int s = wave; s < B; s += nw) {
        const int u  = uid[s];
        const int it = iid[s];
        const float pu = part[(size_t)u * DD + lane];
        const float pi = part[(size_t)(USER_NUM + it) * DD + lane];
        const float x  = pu + pi;
        const float o1 = (x > 0.f) ? x : 0.f;
        float acc_a = bias2, acc_b = 0.f;
#pragma unroll
        for (int k = 0; k < DD; k += 2) {
            acc_a = fmaf(__shfl(o1, k),     sW2[k * 32 + (lane & 31)],       acc_a);
            acc_b = fmaf(__shfl(o1, k + 1), sW2[(k + 1) * 32 + (lane & 31)], acc_b);
        }
        const float a2 = acc_a + acc_b;
        const float o2 = (a2 > 0.f) ? a2 : 0.f;
        float p = o2 * w3v;
        p += __shfl_xor(p, 1);
        p += __shfl_xor(p, 2);
        p += __shfl_xor(p, 4);
        p += __shfl_xor(p, 8);
        p += __shfl_xor(p, 16);
        if (lane == 0) out[s] = p + bias3;
    }
}

extern "C" void kernel_launch(void* const* d_in, const int* in_sizes, int n_in,
                              void* d_out, int out_size, void* d_ws, size_t ws_size,
                              hipStream_t stream) {
    const float* ue   = (const float*)d_in[0];
    const float* ie   = (const float*)d_in[1];
    const int*   erow = (const int*)d_in[2];
    const int*   ecol = (const int*)d_in[3];
    const float* evalp= (const float*)d_in[4];
    const float* Wg1  = (const float*)d_in[5];
    const float* bg1  = (const float*)d_in[6];
    const float* Wg2  = (const float*)d_in[7];
    const float* bg2  = (const float*)d_in[8];
    const float* W1   = (const float*)d_in[9];
    const float* b1   = (const float*)d_in[10];
    const float* W2   = (const float*)d_in[11];
    const float* b2   = (const float*)d_in[12];
    const float* W3   = (const float*)d_in[13];
    const float* b3   = (const float*)d_in[14];
    const int*   uid  = (const int*)d_in[15];
    const int*   iid  = (const int*)d_in[16];
    float* out = (float*)d_out;

    const int E = in_sizes[2];
    const int B = in_sizes[15];

    // workspace (~53.8 MB):
    //   [lx 17.92MB][lx2 17.92MB][epair 16MB][cnt][cursor][base][csum][coff]
    // h (17.92MB) OVERLAYS [epair..] — all dead once spmm finishes.
    // part reuses lx2 (dead after gcn transform).
    char* ws = (char*)d_ws;
    const size_t nd = (size_t)NNODE * DD;
    float* lx    = (float*)ws;
    float* lx2   = lx + nd;
    float* part  = lx2;                                     // alias (lx2 dead)
    char*  tail  = ws + 2 * nd * sizeof(float);
    int2*  epair = (int2*)tail;
    int*   cnt   = (int*)(tail + (size_t)E * sizeof(int2));
    int*   cursor= cnt + NNODE;
    int*   base  = cursor + NNODE;                          // NNODE+1 ints
    int*   csum  = base + NNODE + 1;                        // NCHUNK ints
    int*   coff  = csum + NCHUNK;                           // NCHUNK ints
    float* h     = (float*)tail;                            // overlays epair..

    hipMemsetAsync(cnt, 0, NNODE * sizeof(int), stream);

    hist_kernel<<<2048, 256, 0, stream>>>(erow, cnt, E);
    chunksum_kernel<<<NCHUNK, 256, 0, stream>>>(cnt, csum);
    scan_small_kernel<<<1, 128, 0, stream>>>(csum, coff);
    fill_kernel<<<NCHUNK, 256, 0, stream>>>(cnt, coff, base, cursor);
    scatter_kernel<<<8 * NSTRIPE, 256, 0, stream>>>(erow, ecol, evalp, cursor, epair, E);
    spmm_kernel<<<4096, 256, 0, stream>>>(ue, ie, epair, base, lx, lx2);

    // h = leaky_relu(a1@Wg1 + a2@Wg2 + bg1 + bg2)
    xform_kernel<true><<<(NNODE + 63) / 64, 256, 0, stream>>>(
        lx, lx2, Wg1, Wg2, bg1, bg2, h, NNODE);
    // part (layer-1 partial): users then items
    xform_kernel<false><<<(USER_NUM + 63) / 64, 256, 0, stream>>>(
        ue, h, W1, W1 + DD * DD, b1, nullptr, part, USER_NUM);
    xform_kernel<false><<<(ITEM_NUM + 63) / 64, 256, 0, stream>>>(
        ie, h + (size_t)USER_NUM * DD, W1 + 2 * DD * DD, W1 + 3 * DD * DD,
        nullptr, nullptr, part + (size_t)USER_NUM * DD, ITEM_NUM);

    mlp_kernel<<<1024, 256, 0, stream>>>(part, W2, b2, W3, b3, uid, iid, out, B);
}